// Round 16
// baseline (719.629 us; speedup 1.0000x reference)
//
#include <hip/hip_runtime.h>
#include <hip/hip_bf16.h>

typedef __hip_bfloat16 bf16;
typedef __attribute__((ext_vector_type(8))) short bf16x8;
typedef __attribute__((ext_vector_type(4))) float f32x4;

#define B_ 8
#define S_ 512
#define D_ 1024
#define H_ 16
#define NEGV -9.0e15f
#define WSL 1048576ull
#define LOG2E 1.4426950408889634f

__device__ __forceinline__ float bf2f(bf16 x) { return __bfloat162float(x); }
__device__ __forceinline__ float us2f(unsigned short u) {
  union { unsigned int i; float f; } c; c.i = ((unsigned int)u) << 16; return c.f;
}
__device__ __forceinline__ unsigned short f2us(float f) {
  bf16 h = __float2bfloat16(f);
  unsigned short u; __builtin_memcpy(&u, &h, 2); return u;
}
__device__ __forceinline__ float ldx(const void* p, size_t i, int isbf) {
  return isbf ? bf2f(((const bf16*)p)[i]) : ((const float*)p)[i];
}
struct F4 { float x, y, z, w; };
__device__ __forceinline__ F4 ld4(const void* p, size_t i, int isbf) {
  F4 r;
  if (isbf) {
    ushort4 u = *(const ushort4*)((const bf16*)p + i);
    r.x = us2f(u.x); r.y = us2f(u.y); r.z = us2f(u.z); r.w = us2f(u.w);
  } else {
    float4 d = *(const float4*)((const float*)p + i);
    r.x = d.x; r.y = d.y; r.z = d.z; r.w = d.w;
  }
  return r;
}
// 8 consecutive elements as bf16x8; converts if source is f32
__device__ __forceinline__ bf16x8 ld8bf(const void* p, size_t i, int isbf) {
  if (isbf) return *(const bf16x8*)((const bf16*)p + i);
  float4 a = *(const float4*)((const float*)p + i);
  float4 b = *(const float4*)((const float*)p + i + 4);
  bf16x8 r;
  r[0] = (short)f2us(a.x); r[1] = (short)f2us(a.y);
  r[2] = (short)f2us(a.z); r[3] = (short)f2us(a.w);
  r[4] = (short)f2us(b.x); r[5] = (short)f2us(b.y);
  r[6] = (short)f2us(b.z); r[7] = (short)f2us(b.w);
  return r;
}
__device__ __forceinline__ f32x4 mfma_bf16(bf16x8 a, bf16x8 b, f32x4 c) {
  return __builtin_amdgcn_mfma_f32_16x16x32_bf16(a, b, c, 0, 0, 0);
}
// Async global->LDS, 16B/lane (round-9 verified: linear dest + pre-swizzled src).
__device__ __forceinline__ void gload16(const bf16* g, short* l) {
  __builtin_amdgcn_global_load_lds(
      (const __attribute__((address_space(1))) void*)g,
      (__attribute__((address_space(3))) void*)l, 16, 0, 0);
}

// Dtype detector (round-3 verified: picks f32 on this harness).
__global__ void detect_k(const void* __restrict__ w, int* __restrict__ flag)
{
  if (threadIdx.x == 0 && blockIdx.x == 0) {
    const unsigned short* u = (const unsigned short*)w;
    int sane = 0;
    for (int i = 0; i < 1024; i += 2) {
      float a = fabsf(us2f(u[i]));
      if (a == 0.f || (a > 9.5e-7f && a < 8.f)) sane++;
    }
    *flag = (sane > 256) ? 1 : 0;
  }
}

// ---------------------------------------------------------------------------
// Merged pre-pass (round-11 verified, kept): [0,6144) cvt qkv->bf16;
// [6144,9472) 13 weight transposes; [9472,10496) mask bit-planes.
// ---------------------------------------------------------------------------
__global__ __launch_bounds__(256)
void prep_k(const void* __restrict__ q, const void* __restrict__ k,
            const void* __restrict__ v, bf16* __restrict__ qkvb,
            const int* __restrict__ grh, unsigned char* __restrict__ maskp,
            const void* __restrict__ Wq, const void* __restrict__ Wk,
            const void* __restrict__ Wv, const void* __restrict__ gate_w,
            const void* __restrict__ sub_w, bf16* __restrict__ Wt,
            const int* __restrict__ dflag)
{
  const int bid = blockIdx.x;
  const int tid = threadIdx.x;
  __shared__ float t[64][68];
  if (bid < 6144) {
    const int isbf = *dflag;
    const int z = bid >> 11, blk = bid & 2047;
    const void* src = z == 0 ? q : (z == 1 ? k : v);
    size_t i = ((size_t)blk * 256 + tid) * 8;
    bf16x8 r = ld8bf(src, i, isbf);
    *(bf16x8*)(qkvb + (size_t)z * 4194304 + i) = r;
  } else if (bid < 9472) {
    const int isbf = *dflag;
    const int tt = bid - 6144;
    const int slot = tt >> 8;
    const int blk = tt & 255;
    const int gsrc[5] = {0, 5, 1, 2, 3};
    const void* W;
    size_t woff;
    if (slot < 3)      { W = slot == 0 ? Wq : (slot == 1 ? Wk : Wv); woff = 0; }
    else if (slot < 8) { W = gate_w; woff = (size_t)gsrc[slot - 3] * WSL; }
    else               { W = sub_w;  woff = (size_t)(slot - 8) * WSL; }
    bf16* out = Wt + (size_t)slot * WSL;
    const int nt = blk & 15, kt = blk >> 4;
    {
      int r = tid >> 4, c4 = (tid & 15) * 4;
      #pragma unroll
      for (int i = 0; i < 4; i++) {
        int rr = r + i * 16;
        F4 vv = ld4(W, woff + (size_t)(kt * 64 + rr) * 1024 + nt * 64 + c4, isbf);
        *(float4*)&t[rr][c4] = make_float4(vv.x, vv.y, vv.z, vv.w);
      }
    }
    __syncthreads();
    {
      int n = tid >> 4, k4 = (tid & 15) * 4;
      #pragma unroll
      for (int i = 0; i < 4; i++) {
        int nn = n + i * 16;
        ushort4 u;
        u.x = f2us(t[k4 + 0][nn]); u.y = f2us(t[k4 + 1][nn]);
        u.z = f2us(t[k4 + 2][nn]); u.w = f2us(t[k4 + 3][nn]);
        *(ushort4*)(out + (size_t)(nt * 64 + nn) * 1024 + kt * 64 + k4) = u;
      }
    }
  } else {
    int tfl = (bid - 9472) * 256 + tid;     // [0, 8*512*64)
    int byte = tfl & 63, qi = (tfl >> 6) & 511, bl = tfl >> 15;
    const int* g = grh + ((size_t)bl * 512 + qi) * 512 + byte * 8;
    int4 a = *(const int4*)g;
    int4 b = *(const int4*)(g + 4);
    int gs[8] = {a.x, a.y, a.z, a.w, b.x, b.y, b.z, b.w};
    unsigned int m0 = 0, m1 = 0, m2 = 0, m3 = 0;
    #pragma unroll
    for (int j = 0; j < 8; j++) {
      int kk = byte * 8 + j;
      int diag = (kk == qi);
      m0 |= (unsigned int)(gs[j] > 1) << j;
      m1 |= (unsigned int)(gs[j] == (diag ? 4 : 2)) << j;
      m2 |= (unsigned int)(gs[j] == (diag ? 4 : 3)) << j;
      m3 |= (unsigned int)(gs[j] == 4) << j;
    }
    size_t o = (size_t)bl * 32768 + (size_t)qi * 64 + byte;
    maskp[o]          = (unsigned char)m0;
    maskp[o + 262144] = (unsigned char)m1;
    maskp[o + 524288] = (unsigned char)m2;
    maskp[o + 786432] = (unsigned char)m3;
  }
}

// ---------------------------------------------------------------------------
// QKV projections, z-batched; async gload16 staging (round-9 verified).
// ---------------------------------------------------------------------------
__global__ __launch_bounds__(256)
void qkv_gemm_k(const bf16* __restrict__ qkvb, const bf16* __restrict__ Wt,
                const void* __restrict__ bqp, const void* __restrict__ bkp,
                const void* __restrict__ bvp, bf16* __restrict__ qbf,
                bf16* __restrict__ kbf, bf16* __restrict__ vtb,
                const int* __restrict__ dflag)
{
  const int isbf = *dflag;
  const int z = blockIdx.z;
  const bf16* A = qkvb + (size_t)z * 4194304;
  const void* bias = z == 0 ? bqp : (z == 1 ? bkp : bvp);
  bf16* outB = z == 0 ? qbf : (z == 1 ? kbf : vtb);
  const bf16* Wz = Wt + (size_t)z * WSL;
  const float scale = z == 0 ? 0.125f : 1.0f;
  const int vtrans = (z == 2);

  __shared__ short As[128 * 64];
  __shared__ short Bs[128 * 64];
  const int tid = threadIdx.x;
  const int w = tid >> 6, ln = tid & 63;
  const int ln15 = ln & 15, quad = ln >> 4;
  const int wm = (w & 1) * 64, wn = (w >> 1) * 64;
  const int bm = blockIdx.x * 128, bn = blockIdx.y * 128;
  const int rbase = w * 8 + (ln >> 3);
  const int goff = ((ln & 7) ^ (ln >> 3)) * 8;
  f32x4 acc[4][4];
  #pragma unroll
  for (int mt = 0; mt < 4; mt++)
    #pragma unroll
    for (int nt = 0; nt < 4; nt++) acc[mt][nt] = (f32x4)(0.0f);

  for (int k0 = 0; k0 < 1024; k0 += 64) {
    #pragma unroll
    for (int i = 0; i < 4; i++) {
      int r = i * 32 + rbase;
      gload16(A + (size_t)(bm + r) * 1024 + k0 + goff,
              &As[(i * 32 + w * 8) * 64]);
      gload16(Wz + (size_t)(bn + r) * 1024 + k0 + goff,
              &Bs[(i * 32 + w * 8) * 64]);
    }
    __syncthreads();
    #pragma unroll
    for (int s = 0; s < 2; s++) {
      bf16x8 af[4], bfr[4];
      #pragma unroll
      for (int t = 0; t < 4; t++) {
        int ra = wm + t * 16 + ln15;
        af[t] = *(bf16x8*)&As[ra * 64 + (((s * 4 + quad) ^ (ra & 7)) * 8)];
        int rb = wn + t * 16 + ln15;
        bfr[t] = *(bf16x8*)&Bs[rb * 64 + (((s * 4 + quad) ^ (rb & 7)) * 8)];
      }
      #pragma unroll
      for (int mt = 0; mt < 4; mt++)
        #pragma unroll
        for (int nt = 0; nt < 4; nt++)
          acc[mt][nt] = mfma_bf16(af[mt], bfr[nt], acc[mt][nt]);
    }
    __syncthreads();
  }

  #pragma unroll
  for (int nt = 0; nt < 4; nt++) {
    int col = bn + wn + nt * 16 + ln15;
    float bv = ldx(bias, col, isbf);
    #pragma unroll
    for (int mt = 0; mt < 4; mt++) {
      #pragma unroll
      for (int r = 0; r < 4; r++) {
        int row = bm + wm + mt * 16 + quad * 4 + r;
        float v = (acc[mt][nt][r] + bv) * scale;
        int bb = row >> 9, s = row & 511;
        int h = col >> 6, d0 = col & 63;
        size_t o = vtrans ? (((size_t)(bb * 16 + h) * 64 + d0) * 512 + s)
                          : (((size_t)(bb * 16 + h) * 512 + s) * 64 + d0);
        outB[o] = __float2bfloat16(v);
      }
    }
  }
}

// ---------------------------------------------------------------------------
// Merged qrel (16384 blocks) + edge h-projections (512 blocks).
// ---------------------------------------------------------------------------
__global__ __launch_bounds__(256)
void qrel_hv_k(const bf16* __restrict__ qbf, const void* __restrict__ rel_emb,
               float* __restrict__ G, const bf16* __restrict__ vt,
               const void* __restrict__ att_w, const void* __restrict__ att_b,
               float* __restrict__ h0, float* __restrict__ h1,
               const int* __restrict__ dflag)
{
  const int bid = blockIdx.x;
  const int tid = threadIdx.x;
  const int isbf = *dflag;
  __shared__ float rel[33][65];
  __shared__ float qw[4][64];
  if (bid < 16384) {
    for (int i = tid; i < 33 * 64; i += 256)
      rel[i >> 6][i & 63] = ldx(rel_emb, i, isbf);
    const int wv = tid >> 6, lane = tid & 63;
    const size_t row = (size_t)bid * 4 + wv;
    qw[wv][lane] = bf2f(qbf[row * 64 + lane]);
    __syncthreads();
    if (lane < 33) {
      float s = 0.f;
      #pragma unroll
      for (int d = 0; d < 64; d++) s += qw[wv][d] * rel[lane][d];
      G[row * 33 + lane] = s;
    }
  } else {
    const int tt = bid - 16384;
    const int bh = tt & 127, z = tt >> 7;
    const int i0s[4] = {6, 0, 2, 4};
    const int i1s[4] = {7, 1, 3, 5};
    const int i0 = i0s[z], i1 = i1s[z];
    float* w0 = rel[0];   // reuse LDS
    float* w1 = rel[1] + 1;
    if (tid < 64) {
      w0[tid] = ldx(att_w, i0 * 64 + tid, isbf);
      w1[tid] = ldx(att_w, i1 * 64 + tid, isbf);
    }
    __syncthreads();
    const bf16* vb = vt + (size_t)bh * 64 * 512 + tid * 2;
    float a00 = 0, a01 = 0, a10 = 0, a11 = 0;
    for (int d = 0; d < 64; d++) {
      ushort2 u = *(const ushort2*)(vb + (size_t)d * 512);
      float f0 = us2f(u.x), f1 = us2f(u.y);
      a00 += f0 * w0[d]; a10 += f1 * w0[d];
      a01 += f0 * w1[d]; a11 += f1 * w1[d];
    }
    float b0 = ldx(att_b, i0, isbf), b1 = ldx(att_b, i1, isbf);
    float* p0 = h0 + (size_t)z * 65536 + (size_t)bh * 512 + tid * 2;
    float* p1 = h1 + (size_t)z * 65536 + (size_t)bh * 512 + tid * 2;
    p0[0] = a00 + b0; p0[1] = a10 + b0;
    p1[0] = a01 + b1; p1[1] = a11 + b1;
  }
}

// ---------------------------------------------------------------------------
// Fully fused main view v7 = v6 + LDS diet for 4 blocks/CU (round-15
// post-mortem: LDS 46.6KB capped occupancy at 3 blocks/CU).
//  - gbuf ALIASES P's first 4.2KB: gbuf's last read is before barrier #2,
//    P's first write is after it -> the existing barrier legalizes overlap.
//  - relbuf stored as bf16 (8.4 -> 4.2KB): rel quant error <= 2^-9*|rel|,
//    weighted by attention weights (sum<=1) -> ~1.6e-4, well in tolerance.
// Total LDS 36.9KB -> 4 blocks/CU (+33%). Math otherwise identical to the
// round-15 passing build.
// ---------------------------------------------------------------------------
__global__ __launch_bounds__(256, 2)
void score_fused_k(const bf16* __restrict__ qbf, const bf16* __restrict__ kbf,
                   const float* __restrict__ G, const bf16* __restrict__ vt,
                   const void* __restrict__ rel_emb, bf16* __restrict__ ctx,
                   void* __restrict__ dout, const int* __restrict__ dflag)
{
  __shared__ __align__(16) char smem[37760];
  short* P = (short*)smem;                          // [0, 32768)
  float* gbuf = (float*)smem;                       // alias P[0..4224)
  unsigned short* relb = (unsigned short*)(smem + 32768);  // 33*64 bf16 = 4224B
  float (*ssumS)[16] = (float(*)[16])(smem + 36992);
  float (*sleS)[16]  = (float(*)[16])(smem + 37248);
  float (*sgeS)[16]  = (float(*)[16])(smem + 37504);
  const int tid = threadIdx.x;
  const int w = tid >> 6, ln = tid & 63;
  const int ln15 = ln & 15, quad = ln >> 4;
  const int rowg = (w >> 1) * 16;
  const int ch = w & 1;
  const int bh = blockIdx.x, qt = blockIdx.y;
  const size_t qrow0 = (size_t)bh * 512 + qt * 32;
  const int isbf = *dflag;

  for (int i = tid; i < 32 * 33; i += 256) {
    int r = i / 33, c = i - r * 33;
    gbuf[i] = G[(qrow0 + r) * 33 + c];
  }
  for (int i = tid; i < 33 * 64; i += 256)
    relb[i] = f2us(ldx(rel_emb, i, isbf));

  const bf16* qrow = qbf + (qrow0 + rowg + ln15) * 64;
  bf16x8 af0 = *(const bf16x8*)(qrow + quad * 8);
  bf16x8 af1 = *(const bf16x8*)(qrow + 32 + quad * 8);
  const bf16* kb = kbf + (size_t)bh * 512 * 64;
  f32x4 acc[16];
  #pragma unroll
  for (int t = 0; t < 16; t++) acc[t] = (f32x4)(0.0f);
  #pragma unroll
  for (int t = 0; t < 16; t++) {
    const bf16* kr = kb + (size_t)(ch * 256 + t * 16 + ln15) * 64 + quad * 8;
    bf16x8 b0 = *(const bf16x8*)kr;
    bf16x8 b1 = *(const bf16x8*)(kr + 32);
    acc[t] = mfma_bf16(af0, b0, acc[t]);
    acc[t] = mfma_bf16(af1, b1, acc[t]);
  }
  __syncthreads();   // #1: gbuf/relb valid

  const int qg = qt * 32 + rowg + quad * 4;
  const int rowl0 = rowg + quad * 4;
  float ssum[4], sle[4], sge[4], inv[4];
  #pragma unroll
  for (int r = 0; r < 4; r++) { ssum[r] = 0.f; sle[r] = 0.f; sge[r] = 0.f; }

  // single fused pass: bias + exp (no max; shift-invariant, |s| small)
  #pragma unroll
  for (int t = 0; t < 16; t++) {
    int k = ch * 256 + t * 16 + ln15;
    #pragma unroll
    for (int r = 0; r < 4; r++) {
      int delta = k - (qg + r);
      int bkt = delta < -16 ? 0 : (delta > 16 ? 32 : delta + 16);
      float s = acc[t][r] + gbuf[(rowl0 + r) * 33 + bkt];
      float p = __builtin_amdgcn_exp2f(s * LOG2E);
      acc[t][r] = p;
      ssum[r] += p;
      if (delta <= -16) sle[r] += p;
      if (delta >= 16) sge[r] += p;
    }
  }
  #pragma unroll
  for (int r = 0; r < 4; r++) {
    #pragma unroll
    for (int off = 1; off < 16; off <<= 1) {
      ssum[r] += __shfl_xor(ssum[r], off);
      sle[r] += __shfl_xor(sle[r], off);
      sge[r] += __shfl_xor(sge[r], off);
    }
  }
  if (ln15 == 0) {
    #pragma unroll
    for (int r = 0; r < 4; r++) {
      ssumS[w][quad * 4 + r] = ssum[r];
      sleS[w][quad * 4 + r] = sle[r];
      sgeS[w][quad * 4 + r] = sge[r];
    }
  }
  __syncthreads();   // #2: partner sums visible; gbuf dead -> P may overwrite
  #pragma unroll
  for (int r = 0; r < 4; r++) {
    float tot = ssum[r] + ssumS[w ^ 1][quad * 4 + r];
    sle[r] += sleS[w ^ 1][quad * 4 + r];
    sge[r] += sgeS[w ^ 1][quad * 4 + r];
    inv[r] = 1.f / tot;
  }

  #pragma unroll
  for (int t2 = 0; t2 < 16; t2++) {
    int gg = t2 * 2 + (ln15 >> 3);
    int slot = gg ^ (quad << 1);
    #pragma unroll
    for (int r = 0; r < 4; r++) {
      int rowL = rowl0 + r;
      P[rowL * 512 + ch * 256 + slot * 8 + (ln15 & 7)] =
          (short)f2us(acc[t2][r] * inv[r]);
    }
  }
  __syncthreads();   // #3: full P tile valid

  if ((bh & 15) == 0) {
    const int bg = bh >> 4;
    for (int i = tid; i < 32 * 64; i += 256) {
      int rowL = i >> 6, g = i & 63;
      int chg = g >> 5, gg = g & 31;
      int slot = gg ^ (((rowL >> 2) & 3) << 1);
      bf16x8 u = *(bf16x8*)&P[rowL * 512 + chg * 256 + slot * 8];
      size_t o = (size_t)4194304 + (size_t)bg * 262144 +
                 (size_t)(qt * 32 + rowL) * 512 + g * 8;
      if (isbf) {
        *(bf16x8*)((bf16*)dout + o) = u;
      } else {
        float4 f0 = make_float4(us2f((unsigned short)u[0]), us2f((unsigned short)u[1]),
                                us2f((unsigned short)u[2]), us2f((unsigned short)u[3]));
        float4 f1 = make_float4(us2f((unsigned short)u[4]), us2f((unsigned short)u[5]),
                                us2f((unsigned short)u[6]), us2f((unsigned short)u[7]));
        *(float4*)((float*)dout + o) = f0;
        *(float4*)((float*)dout + o + 4) = f1;
      }
    }
  }

  const bf16* vb = vt + (size_t)bh * 64 * 512;
  f32x4 pacc[2];
  pacc[0] = (f32x4)(0.0f); pacc[1] = (f32x4)(0.0f);
  const int ra = rowg + ln15;
  const int rsw = ((ln15 >> 2) & 3) << 1;
  #pragma unroll
  for (int h2 = 0; h2 < 2; h2++) {
    #pragma unroll
    for (int kk = 0; kk < 8; kk++) {
      int gg = kk * 4 + quad;
      bf16x8 a = *(bf16x8*)&P[ra * 512 + h2 * 256 + ((gg ^ rsw) * 8)];
      int k0 = h2 * 256 + kk * 32;
      #pragma unroll
      for (int nt2 = 0; nt2 < 2; nt2++) {
        int dcol = ch * 32 + nt2 * 16 + ln15;
        bf16x8 b = *(const bf16x8*)(vb + (size_t)dcol * 512 + k0 + quad * 8);
        pacc[nt2] = mfma_bf16(a, b, pacc[nt2]);
      }
    }
  }

  for (int rr = 1; rr < 32; rr++) {
    float av[4];
    #pragma unroll
    for (int r = 0; r < 4; r++) {
      int k = qg + r + rr - 16;
      av[r] = 0.f;
      if (k >= 0 && k < 512) {
        int g = k >> 3, chg = g >> 5, gg = g & 31;
        int slot = gg ^ (quad << 1);
        av[r] = us2f((unsigned short)P[(rowl0 + r) * 512 + chg * 256 +
                                       slot * 8 + (k & 7)]);
      }
    }
    #pragma unroll
    for (int nt2 = 0; nt2 < 2; nt2++) {
      float relv = us2f(relb[rr * 64 + ch * 32 + nt2 * 16 + ln15]);
      #pragma unroll
      for (int r = 0; r < 4; r++) pacc[nt2][r] += av[r] * relv;
    }
  }

  #pragma unroll
  for (int nt2 = 0; nt2 < 2; nt2++) {
    float r0v = us2f(relb[ch * 32 + nt2 * 16 + ln15]);
    float r32v = us2f(relb[32 * 64 + ch * 32 + nt2 * 16 + ln15]);
    #pragma unroll
    for (int r = 0; r < 4; r++)
      pacc[nt2][r] += sle[r] * inv[r] * r0v + sge[r] * inv[r] * r32v;
  }

  const int bl = bh >> 4, head = bh & 15;
  #pragma unroll
  for (int r = 0; r < 4; r++) {
    int s = qt * 32 + rowl0 + r;
    #pragma unroll
    for (int nt2 = 0; nt2 < 2; nt2++)
      ctx[((size_t)bl * 512 + s) * 1024 + head * 64 + ch * 32 + nt2 * 16 + ln15] =
          __float2bfloat16(pacc[nt2][r]);
  }
}

// ---------------------------------------------------------------------------
// Fused edge view v6 = v5 + split-k MFMA chains for ILP. Round-15
// post-mortem: edge is wave-internal-latency bound (VALU 33%, MFMA 7.5%,
// occ 42% - nothing saturated); phase 2 was three 16-deep SERIAL MFMA
// accumulation chains. Split k into two halves with independent accumulator
// sets (6 chains of 8) f32-added at the end (~ulp reorder). VGPR 48->~60,
// still under the 5-blocks/CU LDS-limited budget of 102.
// ---------------------------------------------------------------------------
__global__ __launch_bounds__(256)
void edge_fused_k(const float* __restrict__ h0, const float* __restrict__ h1,
                  const unsigned char* __restrict__ maskp,
                  const bf16* __restrict__ vt, bf16* __restrict__ ctx5)
{
  __shared__ short P[32 * 512];   // 32 KB, UNNORMALIZED bf16 p
  const int tid = threadIdx.x;
  const int w = tid >> 6, ln = tid & 63;
  const int ln15 = ln & 15, quad = ln >> 4;
  const int bh = blockIdx.x, qt = blockIdx.y, view = blockIdx.z;
  const int bl = bh >> 4;
  bf16* ctx = ctx5 + (size_t)(1 + view) * 4194304;

  // ---- phase 1: rows w*8 .. w*8+7, elementwise only ----
  {
    const float* hjp = h1 + (size_t)view * 65536 + (size_t)bh * 512 + ln * 8;
    float4 hA = *(const float4*)hjp;
    float4 hB = *(const float4*)(hjp + 4);
    float hjv[8] = {hA.x * LOG2E, hA.y * LOG2E, hA.z * LOG2E, hA.w * LOG2E,
                    hB.x * LOG2E, hB.y * LOG2E, hB.z * LOG2E, hB.w * LOG2E};
    const float* h0b = h0 + (size_t)view * 65536 + (size_t)bh * 512 + qt * 32 + w * 8;
    const unsigned char* mrow = maskp + (size_t)view * 262144 + (size_t)bl * 32768
                                + (size_t)(qt * 32 + w * 8) * 64 + ln;
    #pragma unroll
    for (int rr = 0; rr < 8; rr++) {
      unsigned int mb = mrow[rr * 64];
      float hi = h0b[rr] * LOG2E;
      // all-masked row -> store 1.0 everywhere: MFMA rowsum = 512 exactly ->
      // ctx = sum(V)/512 (reference uniform).
      float fb = (__ballot(mb != 0) == 0ull) ? 1.0f : 0.0f;
      int r = w * 8 + rr;
      bf16x8 pv;
      #pragma unroll
      for (int j = 0; j < 8; j++) {
        float ej = hi + hjv[j];
        float lr = fmaxf(ej, 0.01f * ej);       // lrelu (log2-domain)
        float p = __builtin_amdgcn_exp2f(lr);
        p = ((mb >> j) & 1) ? p : fb;
        pv[j] = (short)f2us(p);
      }
      *(bf16x8*)&P[r * 512 + ((ln ^ (r & 7)) * 8)] = pv;
    }
  }
  __syncthreads();

  // ---- phase 2: split-k accumulators (6 independent MFMA chains) ----
  bf16x8 ones;
  #pragma unroll
  for (int j = 0; j < 8; j++) ones[j] = (short)0x3F80;   // bf16 1.0
  const bf16* vb = vt + (size_t)bh * 64 * 512;
  const int m0 = (w >> 1) * 16, d0 = (w & 1) * 32;
  f32x4 accA[2], accB[2], accsA, accsB;
  accA[0] = (f32x4)(0.0f); accA[1] = (f32x4)(0.0f);
  accB[0] = (f32x4)(0.0f); accB[1] = (f32x4)(0.0f);
  accsA = (f32x4)(0.0f); accsB = (f32x4)(0.0f);

  const int ra = m0 + ln15;
  const int rsw = ra & 7;
  #pragma unroll
  for (int kk = 0; kk < 8; kk++) {
    int k0a = kk * 32;               // half A: k in [0,256)
    int k0b = 256 + kk * 32;         // half B: k in [256,512)
    int gA = (k0a >> 3) + quad;
    int gB = (k0b >> 3) + quad;
    bf16x8 aA = *(bf16x8*)&P[ra * 512 + ((gA ^ rsw) * 8)];
    bf16x8 aB = *(bf16x8*)&P[ra * 512 + ((gB ^ rsw) * 8)];
    #pragma unroll
    for (int nt = 0; nt < 2; nt++) {
      const bf16* vrow = vb + (size_t)(d0 + nt * 16 + ln15) * 512 + quad * 8;
      bf16x8 bA = *(const bf16x8*)(vrow + k0a);
      bf16x8 bB = *(const bf16x8*)(vrow + k0b);
      accA[nt] = mfma_bf16(aA, bA, accA[nt]);
      accB[nt] = mfma_bf16(aB, bB, accB[nt]);
    }
    accsA = mfma_bf16(aA, ones, accsA);
    accsB = mfma_bf16(aB, ones, accsB);
  }

  const int head = bh & 15;
  #pragma unroll
  for (int r = 0; r < 4; r++) {
    float sum = accsA[r] + accsB[r];   // > 0 always (1.0-fill if masked)
    float inv = 1.0f / sum;
    int s = qt * 32 + m0 + quad * 4 + r;
    #pragma unroll
    for (int nt = 0; nt < 2; nt++)
      ctx[((size_t)bl * 512 + s) * 1024 + head * 64 + d0 + nt * 16 + ln15] =
          __float2bfloat16((accA[nt][r] + accB[nt][r]) * inv);
  }
}

// ---------------------------------------------------------------------------
// Gate GEMMs, z-batched over 5 views; async gload16 staging.
// ---------------------------------------------------------------------------
__global__ __launch_bounds__(256)
void gate_gemm_k(const bf16* __restrict__ ctx5, const bf16* __restrict__ Wt,
                 const void* __restrict__ gate_b, bf16* __restrict__ gated5,
                 const int* __restrict__ dflag)
{
  const int isbf = *dflag;
  const int z = blockIdx.z;
  const int gsel[5] = {0, 5, 1, 2, 3};
  const bf16* A = ctx5 + (size_t)z * 4194304;
  bf16* outB = gated5 + (size_t)z * 4194304;
  const bf16* Wz = Wt + (size_t)(3 + z) * WSL;
  const size_t boff = (size_t)gsel[z] * 1024;

  __shared__ short As[128 * 64];
  __shared__ short Bs[128 * 64];
  const int tid = threadIdx.x;
  const int w = tid >> 6, ln = tid & 63;
  const int ln15 = ln & 15, quad = ln >> 4;
  const int wm = (w & 1) * 64, wn = (w >> 1) * 64;
  const int bm = blockIdx.x * 128, bn = blockIdx.y * 128;
  const int rbase = w * 8 + (ln >> 3);
  const int goff = ((ln & 7) ^ (ln >> 3)) * 8;
  f32x4 acc[4][4];
  #pragma unroll
  for (int mt = 0; mt < 4; mt++)
    #pragma unroll
    for (int nt = 0; nt < 4; nt++) acc[mt][nt] = (f32x4)(0.0f);

  for (int k0 = 0; k0 < 1024; k0 += 64) {
    #pragma unroll
    for (int i = 0; i < 4; i++) {
      int r = i * 32 + rbase;
      gload16(A + (size_t)(bm + r) * 1024 + k0 + goff,
              &As[(i * 32 + w * 8) * 64]);
      gload16(Wz + (size_t)(bn + r) * 1024 + k0 + goff,
              &Bs[(i * 32 + w * 8) * 64]);
    }
    __syncthreads();
    #pragma unroll
    for (int s = 0; s < 2; s++) {
      bf16x8 af[4], bfr[4];
      #pragma unroll
      for (int t = 0; t < 4; t++) {
        int ra = wm + t * 16 + ln15;
        af[t] = *(bf16x8*)&As[ra * 64 + (((s * 4 + quad) ^ (ra & 7)) * 8)];
        int rb = wn + t * 16 + ln15;
        bfr[t] = *(bf16x8*)&Bs[rb * 64 + (((s * 4 + quad) ^ (rb & 7)) * 8)];
      }
      #pragma unroll
      for (int mt = 0; mt < 4; mt++)
        #pragma unroll
        for (int nt = 0; nt < 4; nt++)
          acc[mt][nt] = mfma_bf16(af[mt], bfr[nt], acc[mt][nt]);
    }
    __syncthreads();
  }

  #pragma unroll
  for (int nt = 0; nt < 4; nt++) {
    int col = bn + wn + nt * 16 + ln15;
    float bv = ldx(gate_b, boff + col, isbf);
    #pragma unroll
    for (int mt = 0; mt < 4; mt++) {
      #pragma unroll
      for (int r = 0; r < 4; r++) {
        int row = bm + wm + mt * 16 + quad * 4 + r;
        float v = acc[mt][nt][r] + bv;
        float x = bf2f(A[(size_t)row * 1024 + col]);
        outB[(size_t)row * 1024 + col] = __float2bfloat16(x / (1.f + __expf(-v)));
      }
    }
  }
}

// ---------------------------------------------------------------------------
// Sub GEMM, split-K x2 (round-12 verified): each z handles 2560 of K=5120,
// writes f32 partials into the dead ctx5 region; finish2_k combines + bias.
// ---------------------------------------------------------------------------
__global__ __launch_bounds__(256)
void sub_gemm_k(const bf16* __restrict__ gated5, const bf16* __restrict__ Wt,
                float* __restrict__ part)
{
  __shared__ short As[128 * 64];
  __shared__ short Bs[128 * 64];
  const int tid = threadIdx.x;
  const int w = tid >> 6, ln = tid & 63;
  const int ln15 = ln & 15, quad = ln >> 4;
  const int wm = (w & 1) * 64, wn = (w >> 1) * 64;
  const int bm = blockIdx.x * 128, bn = blockIdx.y * 128;
  const int zk = blockIdx.z;
  const int rbase = w * 8 + (ln >> 3);
  const int goff = ((ln & 7) ^ (ln >> 3)) * 8;
  f32x4 acc[4][4];
  #pragma unroll
  for (int mt = 0; mt < 4; mt++)
    #pragma unroll
    for (int nt = 0; nt < 4; nt++) acc[mt][nt] = (f32x4)(0.0f);

  for (int k0 = zk * 2560; k0 < (zk + 1) * 2560; k0 += 64) {
    const int slot = k0 >> 10, kk = k0 & 1023;
    const bf16* Ab = gated5 + (size_t)slot * 4194304;
    const bf16* Wz = Wt + (size_t)(8 + slot) * WSL;
    #pragma unroll
    for (int i = 0; i < 4; i++) {
      int r = i * 32 + rbase;
      gload16(Ab + (size_t)(bm + r) * 1024 + kk + goff,
              &As[(i * 32 + w * 8) * 64]);
      gload16(Wz + (size_t)(bn + r) * 1024 + kk + goff,
              &Bs[(i * 32 + w * 8) * 64]);
    }
    __syncthreads();
    #pragma unroll
    for (int s = 0; s < 2; s++) {
      bf16x8 af[4], bfr[4];
      #pragma unroll
      for (int t = 0; t < 4; t++) {
        int ra = wm + t * 16 + ln15;
        af[t] = *(bf16x8*)&As[ra * 64 + (((s * 4 + quad) ^ (ra & 7)) * 8)];
        int rb = wn + t * 16 + ln15;
        bfr[t] = *(bf16x8*)&Bs[rb * 64 + (((s * 4 + quad) ^ (rb & 7)) * 8)];
      }
      #pragma unroll
      for (int mt = 0; mt < 4; mt++)
        #pragma unroll
        for (int nt = 0; nt < 4; nt++)
          acc[mt][nt] = mfma_bf16(af[mt], bfr[nt], acc[mt][nt]);
    }
    __syncthreads();
  }

  float* pz = part + (size_t)zk * 4194304;
  #pragma unroll
  for (int nt = 0; nt < 4; nt++) {
    int col = bn + wn + nt * 16 + ln15;
    #pragma unroll
    for (int mt = 0; mt < 4; mt++) {
      #pragma unroll
      for (int r = 0; r < 4; r++) {
        int row = bm + wm + mt * 16 + quad * 4 + r;
        pz[(size_t)row * 1024 + col] = acc[mt][nt][r];
      }
    }
  }
}

// ---------------------------------------------------------------------------
// Combine split-K partials + sub_b -> d_out (dtype-aware).
// ---------------------------------------------------------------------------
__global__ __launch_bounds__(256)
void finish2_k(const float* __restrict__ part, const void* __restrict__ sub_b,
               void* __restrict__ dout, const int* __restrict__ dflag)
{
  const int isbf = *dflag;
  int i = blockIdx.x * 256 + threadIdx.x;
  float4 a = ((const float4*)part)[i];
  float4 b = ((const float4*)(part + 4194304))[i];
  int c = (i * 4) & 1023;
  float o0 = a.x + b.x + ldx(sub_b, c + 0, isbf);
  float o1 = a.y + b.y + ldx(sub_b, c + 1, isbf);
  float o2 = a.z + b.z + ldx(sub_b, c + 2, isbf);
  float o3 = a.w + b.w + ldx(sub_b, c + 3, isbf);
  if (isbf) {
    ushort4 u;
    u.x = f2us(o0); u.y = f2us(o1); u.z = f2us(o2); u.w = f2us(o3);
    ((ushort4*)dout)[i] = u;
  } else {
    ((float4*)dout)[i] = make_float4(o0, o1, o2, o3);
  }
}

// ---------------------------------------------------------------------------
extern "C" void kernel_launch(void* const* d_in, const int* in_sizes, int n_in,
                              void* d_out, int out_size, void* d_ws, size_t ws_size,
                              hipStream_t stream)
{
  const void* key   = d_in[0];
  const void* value = d_in[1];
  const void* query = d_in[2];
  const int*  grh   = (const int*)d_in[3];
  const void* Wq = d_in[5];
  const void* bq = d_in[6];
  const void* Wk = d_in[7];
  const void* bk = d_in[8];
  const void* Wv = d_in[9];
  const void* bv = d_in[10];
  const void* rel_emb = d_in[11];
  const void* att_w = d_in[12];
  const void* att_b = d_in[13];
  const void* gate_w = d_in[14];
  const void* gate_b = d_in[15];
  const void* sub_w = d_in[16];
  const void* sub_b = d_in[17];

  // workspace layout (floats) — same footprint as rounds 9-15 (~173 MB)
  int* dflag = (int*)d_ws;
  float* base = (float*)d_ws;
  bf16* qbf = (bf16*)(base + 16);
  bf16* kbf = (bf16*)(base + 16 + 2097152);
  bf16* vtb = (bf16*)(base + 16 + 2 * 2097152);
  bf16* Wt  = (bf16*)(base + 16 + 3 * 2097152);
  float* G  = base + 16 + 3 * 2097152 + 6815744;
  float* h0 = G + 2162688;
  float* h1 = h0 + 262144;
  bf16* ctx5   = (bf16*)(h1 + 262144);
  bf16* gated5 = ctx5 + 5ull * 4194304;
  unsigned char* maskp = (unsigned char*)(gated5 + 5ull * 4194304);
  bf16* qkvb = (bf16*)(maskp + 1048576);
  float* subpart = (float*)ctx5;   // ctx5 dead after gate_gemm; 33.5MB fits 42MB

  detect_k<<<dim3(1), dim3(64), 0, stream>>>(Wq, dflag);

  // merged pre-pass: cvt (6144) + wtrans (3328) + mask_pack (1024)
  prep_k<<<dim3(10496), dim3(256), 0, stream>>>(
      query, key, value, qkvb, grh, maskp, Wq, Wk, Wv, gate_w, sub_w, Wt, dflag);

  // QKV projections batched (z: 0=q scaled, 1=k, 2=v transposed)
  qkv_gemm_k<<<dim3(32, 8, 3), dim3(256), 0, stream>>>(
      qkvb, Wt, bq, bk, bv, qbf, kbf, vtb, dflag);

  // merged qrel (16384) + hv (512)
  qrel_hv_k<<<dim3(16896), dim3(256), 0, stream>>>(
      qbf, rel_emb, G, vtb, att_w, att_b, h0, h1, dflag);

  // main view fully fused -> ctx5 slot 0 (+ top_attn to d_out)
  score_fused_k<<<dim3(128, 16), dim3(256), 0, stream>>>(
      qbf, kbf, G, vtb, rel_emb, ctx5, d_out, dflag);

  // edge views fused softmax+PV -> ctx5 slots 1..4
  edge_fused_k<<<dim3(128, 16, 4), dim3(256), 0, stream>>>(
      h0, h1, maskp, vtb, ctx5);

  // 5 gate GEMMs batched, then split-K sub GEMM + combine
  gate_gemm_k<<<dim3(32, 8, 5), dim3(256), 0, stream>>>(
      ctx5, Wt, gate_b, gated5, dflag);
  sub_gemm_k<<<dim3(32, 8, 2), dim3(256), 0, stream>>>(
      gated5, Wt, subpart);
  finish2_k<<<dim3(4096), dim3(256), 0, stream>>>(
      subpart, sub_b, d_out, dflag);
}

// Round 17
// 706.645 us; speedup vs baseline: 1.0184x; 1.0184x over previous
//
#include <hip/hip_runtime.h>
#include <hip/hip_bf16.h>

typedef __hip_bfloat16 bf16;
typedef __attribute__((ext_vector_type(8))) short bf16x8;
typedef __attribute__((ext_vector_type(4))) float f32x4;

#define B_ 8
#define S_ 512
#define D_ 1024
#define H_ 16
#define NEGV -9.0e15f
#define WSL 1048576ull
#define LOG2E 1.4426950408889634f

__device__ __forceinline__ float bf2f(bf16 x) { return __bfloat162float(x); }
__device__ __forceinline__ float us2f(unsigned short u) {
  union { unsigned int i; float f; } c; c.i = ((unsigned int)u) << 16; return c.f;
}
__device__ __forceinline__ unsigned short f2us(float f) {
  bf16 h = __float2bfloat16(f);
  unsigned short u; __builtin_memcpy(&u, &h, 2); return u;
}
__device__ __forceinline__ float ldx(const void* p, size_t i, int isbf) {
  return isbf ? bf2f(((const bf16*)p)[i]) : ((const float*)p)[i];
}
struct F4 { float x, y, z, w; };
__device__ __forceinline__ F4 ld4(const void* p, size_t i, int isbf) {
  F4 r;
  if (isbf) {
    ushort4 u = *(const ushort4*)((const bf16*)p + i);
    r.x = us2f(u.x); r.y = us2f(u.y); r.z = us2f(u.z); r.w = us2f(u.w);
  } else {
    float4 d = *(const float4*)((const float*)p + i);
    r.x = d.x; r.y = d.y; r.z = d.z; r.w = d.w;
  }
  return r;
}
// 8 consecutive elements as bf16x8; converts if source is f32
__device__ __forceinline__ bf16x8 ld8bf(const void* p, size_t i, int isbf) {
  if (isbf) return *(const bf16x8*)((const bf16*)p + i);
  float4 a = *(const float4*)((const float*)p + i);
  float4 b = *(const float4*)((const float*)p + i + 4);
  bf16x8 r;
  r[0] = (short)f2us(a.x); r[1] = (short)f2us(a.y);
  r[2] = (short)f2us(a.z); r[3] = (short)f2us(a.w);
  r[4] = (short)f2us(b.x); r[5] = (short)f2us(b.y);
  r[6] = (short)f2us(b.z); r[7] = (short)f2us(b.w);
  return r;
}
__device__ __forceinline__ f32x4 mfma_bf16(bf16x8 a, bf16x8 b, f32x4 c) {
  return __builtin_amdgcn_mfma_f32_16x16x32_bf16(a, b, c, 0, 0, 0);
}
// Async global->LDS, 16B/lane (round-9 verified: linear dest + pre-swizzled src).
__device__ __forceinline__ void gload16(const bf16* g, short* l) {
  __builtin_amdgcn_global_load_lds(
      (const __attribute__((address_space(1))) void*)g,
      (__attribute__((address_space(3))) void*)l, 16, 0, 0);
}

// Dtype detector (round-3 verified: picks f32 on this harness).
__global__ void detect_k(const void* __restrict__ w, int* __restrict__ flag)
{
  if (threadIdx.x == 0 && blockIdx.x == 0) {
    const unsigned short* u = (const unsigned short*)w;
    int sane = 0;
    for (int i = 0; i < 1024; i += 2) {
      float a = fabsf(us2f(u[i]));
      if (a == 0.f || (a > 9.5e-7f && a < 8.f)) sane++;
    }
    *flag = (sane > 256) ? 1 : 0;
  }
}

// ---------------------------------------------------------------------------
// Merged pre-pass (round-11 verified, kept): [0,6144) cvt qkv->bf16;
// [6144,9472) 13 weight transposes; [9472,10496) mask bit-planes.
// ---------------------------------------------------------------------------
__global__ __launch_bounds__(256)
void prep_k(const void* __restrict__ q, const void* __restrict__ k,
            const void* __restrict__ v, bf16* __restrict__ qkvb,
            const int* __restrict__ grh, unsigned char* __restrict__ maskp,
            const void* __restrict__ Wq, const void* __restrict__ Wk,
            const void* __restrict__ Wv, const void* __restrict__ gate_w,
            const void* __restrict__ sub_w, bf16* __restrict__ Wt,
            const int* __restrict__ dflag)
{
  const int bid = blockIdx.x;
  const int tid = threadIdx.x;
  __shared__ float t[64][68];
  if (bid < 6144) {
    const int isbf = *dflag;
    const int z = bid >> 11, blk = bid & 2047;
    const void* src = z == 0 ? q : (z == 1 ? k : v);
    size_t i = ((size_t)blk * 256 + tid) * 8;
    bf16x8 r = ld8bf(src, i, isbf);
    *(bf16x8*)(qkvb + (size_t)z * 4194304 + i) = r;
  } else if (bid < 9472) {
    const int isbf = *dflag;
    const int tt = bid - 6144;
    const int slot = tt >> 8;
    const int blk = tt & 255;
    const int gsrc[5] = {0, 5, 1, 2, 3};
    const void* W;
    size_t woff;
    if (slot < 3)      { W = slot == 0 ? Wq : (slot == 1 ? Wk : Wv); woff = 0; }
    else if (slot < 8) { W = gate_w; woff = (size_t)gsrc[slot - 3] * WSL; }
    else               { W = sub_w;  woff = (size_t)(slot - 8) * WSL; }
    bf16* out = Wt + (size_t)slot * WSL;
    const int nt = blk & 15, kt = blk >> 4;
    {
      int r = tid >> 4, c4 = (tid & 15) * 4;
      #pragma unroll
      for (int i = 0; i < 4; i++) {
        int rr = r + i * 16;
        F4 vv = ld4(W, woff + (size_t)(kt * 64 + rr) * 1024 + nt * 64 + c4, isbf);
        *(float4*)&t[rr][c4] = make_float4(vv.x, vv.y, vv.z, vv.w);
      }
    }
    __syncthreads();
    {
      int n = tid >> 4, k4 = (tid & 15) * 4;
      #pragma unroll
      for (int i = 0; i < 4; i++) {
        int nn = n + i * 16;
        ushort4 u;
        u.x = f2us(t[k4 + 0][nn]); u.y = f2us(t[k4 + 1][nn]);
        u.z = f2us(t[k4 + 2][nn]); u.w = f2us(t[k4 + 3][nn]);
        *(ushort4*)(out + (size_t)(nt * 64 + nn) * 1024 + kt * 64 + k4) = u;
      }
    }
  } else {
    int tfl = (bid - 9472) * 256 + tid;     // [0, 8*512*64)
    int byte = tfl & 63, qi = (tfl >> 6) & 511, bl = tfl >> 15;
    const int* g = grh + ((size_t)bl * 512 + qi) * 512 + byte * 8;
    int4 a = *(const int4*)g;
    int4 b = *(const int4*)(g + 4);
    int gs[8] = {a.x, a.y, a.z, a.w, b.x, b.y, b.z, b.w};
    unsigned int m0 = 0, m1 = 0, m2 = 0, m3 = 0;
    #pragma unroll
    for (int j = 0; j < 8; j++) {
      int kk = byte * 8 + j;
      int diag = (kk == qi);
      m0 |= (unsigned int)(gs[j] > 1) << j;
      m1 |= (unsigned int)(gs[j] == (diag ? 4 : 2)) << j;
      m2 |= (unsigned int)(gs[j] == (diag ? 4 : 3)) << j;
      m3 |= (unsigned int)(gs[j] == 4) << j;
    }
    size_t o = (size_t)bl * 32768 + (size_t)qi * 64 + byte;
    maskp[o]          = (unsigned char)m0;
    maskp[o + 262144] = (unsigned char)m1;
    maskp[o + 524288] = (unsigned char)m2;
    maskp[o + 786432] = (unsigned char)m3;
  }
}

// ---------------------------------------------------------------------------
// QKV projections, z-batched; async gload16 staging (round-9 verified).
// ---------------------------------------------------------------------------
__global__ __launch_bounds__(256)
void qkv_gemm_k(const bf16* __restrict__ qkvb, const bf16* __restrict__ Wt,
                const void* __restrict__ bqp, const void* __restrict__ bkp,
                const void* __restrict__ bvp, bf16* __restrict__ qbf,
                bf16* __restrict__ kbf, bf16* __restrict__ vtb,
                const int* __restrict__ dflag)
{
  const int isbf = *dflag;
  const int z = blockIdx.z;
  const bf16* A = qkvb + (size_t)z * 4194304;
  const void* bias = z == 0 ? bqp : (z == 1 ? bkp : bvp);
  bf16* outB = z == 0 ? qbf : (z == 1 ? kbf : vtb);
  const bf16* Wz = Wt + (size_t)z * WSL;
  const float scale = z == 0 ? 0.125f : 1.0f;
  const int vtrans = (z == 2);

  __shared__ short As[128 * 64];
  __shared__ short Bs[128 * 64];
  const int tid = threadIdx.x;
  const int w = tid >> 6, ln = tid & 63;
  const int ln15 = ln & 15, quad = ln >> 4;
  const int wm = (w & 1) * 64, wn = (w >> 1) * 64;
  const int bm = blockIdx.x * 128, bn = blockIdx.y * 128;
  const int rbase = w * 8 + (ln >> 3);
  const int goff = ((ln & 7) ^ (ln >> 3)) * 8;
  f32x4 acc[4][4];
  #pragma unroll
  for (int mt = 0; mt < 4; mt++)
    #pragma unroll
    for (int nt = 0; nt < 4; nt++) acc[mt][nt] = (f32x4)(0.0f);

  for (int k0 = 0; k0 < 1024; k0 += 64) {
    #pragma unroll
    for (int i = 0; i < 4; i++) {
      int r = i * 32 + rbase;
      gload16(A + (size_t)(bm + r) * 1024 + k0 + goff,
              &As[(i * 32 + w * 8) * 64]);
      gload16(Wz + (size_t)(bn + r) * 1024 + k0 + goff,
              &Bs[(i * 32 + w * 8) * 64]);
    }
    __syncthreads();
    #pragma unroll
    for (int s = 0; s < 2; s++) {
      bf16x8 af[4], bfr[4];
      #pragma unroll
      for (int t = 0; t < 4; t++) {
        int ra = wm + t * 16 + ln15;
        af[t] = *(bf16x8*)&As[ra * 64 + (((s * 4 + quad) ^ (ra & 7)) * 8)];
        int rb = wn + t * 16 + ln15;
        bfr[t] = *(bf16x8*)&Bs[rb * 64 + (((s * 4 + quad) ^ (rb & 7)) * 8)];
      }
      #pragma unroll
      for (int mt = 0; mt < 4; mt++)
        #pragma unroll
        for (int nt = 0; nt < 4; nt++)
          acc[mt][nt] = mfma_bf16(af[mt], bfr[nt], acc[mt][nt]);
    }
    __syncthreads();
  }

  #pragma unroll
  for (int nt = 0; nt < 4; nt++) {
    int col = bn + wn + nt * 16 + ln15;
    float bv = ldx(bias, col, isbf);
    #pragma unroll
    for (int mt = 0; mt < 4; mt++) {
      #pragma unroll
      for (int r = 0; r < 4; r++) {
        int row = bm + wm + mt * 16 + quad * 4 + r;
        float v = (acc[mt][nt][r] + bv) * scale;
        int bb = row >> 9, s = row & 511;
        int h = col >> 6, d0 = col & 63;
        size_t o = vtrans ? (((size_t)(bb * 16 + h) * 64 + d0) * 512 + s)
                          : (((size_t)(bb * 16 + h) * 512 + s) * 64 + d0);
        outB[o] = __float2bfloat16(v);
      }
    }
  }
}

// ---------------------------------------------------------------------------
// Merged qrel (16384 blocks) + edge h-projections (512 blocks).
// ---------------------------------------------------------------------------
__global__ __launch_bounds__(256)
void qrel_hv_k(const bf16* __restrict__ qbf, const void* __restrict__ rel_emb,
               float* __restrict__ G, const bf16* __restrict__ vt,
               const void* __restrict__ att_w, const void* __restrict__ att_b,
               float* __restrict__ h0, float* __restrict__ h1,
               const int* __restrict__ dflag)
{
  const int bid = blockIdx.x;
  const int tid = threadIdx.x;
  const int isbf = *dflag;
  __shared__ float rel[33][65];
  __shared__ float qw[4][64];
  if (bid < 16384) {
    for (int i = tid; i < 33 * 64; i += 256)
      rel[i >> 6][i & 63] = ldx(rel_emb, i, isbf);
    const int wv = tid >> 6, lane = tid & 63;
    const size_t row = (size_t)bid * 4 + wv;
    qw[wv][lane] = bf2f(qbf[row * 64 + lane]);
    __syncthreads();
    if (lane < 33) {
      float s = 0.f;
      #pragma unroll
      for (int d = 0; d < 64; d++) s += qw[wv][d] * rel[lane][d];
      G[row * 33 + lane] = s;
    }
  } else {
    const int tt = bid - 16384;
    const int bh = tt & 127, z = tt >> 7;
    const int i0s[4] = {6, 0, 2, 4};
    const int i1s[4] = {7, 1, 3, 5};
    const int i0 = i0s[z], i1 = i1s[z];
    float* w0 = rel[0];   // reuse LDS
    float* w1 = rel[1] + 1;
    if (tid < 64) {
      w0[tid] = ldx(att_w, i0 * 64 + tid, isbf);
      w1[tid] = ldx(att_w, i1 * 64 + tid, isbf);
    }
    __syncthreads();
    const bf16* vb = vt + (size_t)bh * 64 * 512 + tid * 2;
    float a00 = 0, a01 = 0, a10 = 0, a11 = 0;
    for (int d = 0; d < 64; d++) {
      ushort2 u = *(const ushort2*)(vb + (size_t)d * 512);
      float f0 = us2f(u.x), f1 = us2f(u.y);
      a00 += f0 * w0[d]; a10 += f1 * w0[d];
      a01 += f0 * w1[d]; a11 += f1 * w1[d];
    }
    float b0 = ldx(att_b, i0, isbf), b1 = ldx(att_b, i1, isbf);
    float* p0 = h0 + (size_t)z * 65536 + (size_t)bh * 512 + tid * 2;
    float* p1 = h1 + (size_t)z * 65536 + (size_t)bh * 512 + tid * 2;
    p0[0] = a00 + b0; p0[1] = a10 + b0;
    p1[0] = a01 + b1; p1[1] = a11 + b1;
  }
}

// ---------------------------------------------------------------------------
// Fully fused main view v7 (round-16 verified): single-pass softmax + LDS
// diet (gbuf aliases P; rel as bf16; 36.9KB total).
// ---------------------------------------------------------------------------
__global__ __launch_bounds__(256, 2)
void score_fused_k(const bf16* __restrict__ qbf, const bf16* __restrict__ kbf,
                   const float* __restrict__ G, const bf16* __restrict__ vt,
                   const void* __restrict__ rel_emb, bf16* __restrict__ ctx,
                   void* __restrict__ dout, const int* __restrict__ dflag)
{
  __shared__ __align__(16) char smem[37760];
  short* P = (short*)smem;                          // [0, 32768)
  float* gbuf = (float*)smem;                       // alias P[0..4224)
  unsigned short* relb = (unsigned short*)(smem + 32768);  // 33*64 bf16 = 4224B
  float (*ssumS)[16] = (float(*)[16])(smem + 36992);
  float (*sleS)[16]  = (float(*)[16])(smem + 37248);
  float (*sgeS)[16]  = (float(*)[16])(smem + 37504);
  const int tid = threadIdx.x;
  const int w = tid >> 6, ln = tid & 63;
  const int ln15 = ln & 15, quad = ln >> 4;
  const int rowg = (w >> 1) * 16;
  const int ch = w & 1;
  const int bh = blockIdx.x, qt = blockIdx.y;
  const size_t qrow0 = (size_t)bh * 512 + qt * 32;
  const int isbf = *dflag;

  for (int i = tid; i < 32 * 33; i += 256) {
    int r = i / 33, c = i - r * 33;
    gbuf[i] = G[(qrow0 + r) * 33 + c];
  }
  for (int i = tid; i < 33 * 64; i += 256)
    relb[i] = f2us(ldx(rel_emb, i, isbf));

  const bf16* qrow = qbf + (qrow0 + rowg + ln15) * 64;
  bf16x8 af0 = *(const bf16x8*)(qrow + quad * 8);
  bf16x8 af1 = *(const bf16x8*)(qrow + 32 + quad * 8);
  const bf16* kb = kbf + (size_t)bh * 512 * 64;
  f32x4 acc[16];
  #pragma unroll
  for (int t = 0; t < 16; t++) acc[t] = (f32x4)(0.0f);
  #pragma unroll
  for (int t = 0; t < 16; t++) {
    const bf16* kr = kb + (size_t)(ch * 256 + t * 16 + ln15) * 64 + quad * 8;
    bf16x8 b0 = *(const bf16x8*)kr;
    bf16x8 b1 = *(const bf16x8*)(kr + 32);
    acc[t] = mfma_bf16(af0, b0, acc[t]);
    acc[t] = mfma_bf16(af1, b1, acc[t]);
  }
  __syncthreads();   // #1: gbuf/relb valid

  const int qg = qt * 32 + rowg + quad * 4;
  const int rowl0 = rowg + quad * 4;
  float ssum[4], sle[4], sge[4], inv[4];
  #pragma unroll
  for (int r = 0; r < 4; r++) { ssum[r] = 0.f; sle[r] = 0.f; sge[r] = 0.f; }

  // single fused pass: bias + exp (no max; shift-invariant, |s| small)
  #pragma unroll
  for (int t = 0; t < 16; t++) {
    int k = ch * 256 + t * 16 + ln15;
    #pragma unroll
    for (int r = 0; r < 4; r++) {
      int delta = k - (qg + r);
      int bkt = delta < -16 ? 0 : (delta > 16 ? 32 : delta + 16);
      float s = acc[t][r] + gbuf[(rowl0 + r) * 33 + bkt];
      float p = __builtin_amdgcn_exp2f(s * LOG2E);
      acc[t][r] = p;
      ssum[r] += p;
      if (delta <= -16) sle[r] += p;
      if (delta >= 16) sge[r] += p;
    }
  }
  #pragma unroll
  for (int r = 0; r < 4; r++) {
    #pragma unroll
    for (int off = 1; off < 16; off <<= 1) {
      ssum[r] += __shfl_xor(ssum[r], off);
      sle[r] += __shfl_xor(sle[r], off);
      sge[r] += __shfl_xor(sge[r], off);
    }
  }
  if (ln15 == 0) {
    #pragma unroll
    for (int r = 0; r < 4; r++) {
      ssumS[w][quad * 4 + r] = ssum[r];
      sleS[w][quad * 4 + r] = sle[r];
      sgeS[w][quad * 4 + r] = sge[r];
    }
  }
  __syncthreads();   // #2: partner sums visible; gbuf dead -> P may overwrite
  #pragma unroll
  for (int r = 0; r < 4; r++) {
    float tot = ssum[r] + ssumS[w ^ 1][quad * 4 + r];
    sle[r] += sleS[w ^ 1][quad * 4 + r];
    sge[r] += sgeS[w ^ 1][quad * 4 + r];
    inv[r] = 1.f / tot;
  }

  #pragma unroll
  for (int t2 = 0; t2 < 16; t2++) {
    int gg = t2 * 2 + (ln15 >> 3);
    int slot = gg ^ (quad << 1);
    #pragma unroll
    for (int r = 0; r < 4; r++) {
      int rowL = rowl0 + r;
      P[rowL * 512 + ch * 256 + slot * 8 + (ln15 & 7)] =
          (short)f2us(acc[t2][r] * inv[r]);
    }
  }
  __syncthreads();   // #3: full P tile valid

  if ((bh & 15) == 0) {
    const int bg = bh >> 4;
    for (int i = tid; i < 32 * 64; i += 256) {
      int rowL = i >> 6, g = i & 63;
      int chg = g >> 5, gg = g & 31;
      int slot = gg ^ (((rowL >> 2) & 3) << 1);
      bf16x8 u = *(bf16x8*)&P[rowL * 512 + chg * 256 + slot * 8];
      size_t o = (size_t)4194304 + (size_t)bg * 262144 +
                 (size_t)(qt * 32 + rowL) * 512 + g * 8;
      if (isbf) {
        *(bf16x8*)((bf16*)dout + o) = u;
      } else {
        float4 f0 = make_float4(us2f((unsigned short)u[0]), us2f((unsigned short)u[1]),
                                us2f((unsigned short)u[2]), us2f((unsigned short)u[3]));
        float4 f1 = make_float4(us2f((unsigned short)u[4]), us2f((unsigned short)u[5]),
                                us2f((unsigned short)u[6]), us2f((unsigned short)u[7]));
        *(float4*)((float*)dout + o) = f0;
        *(float4*)((float*)dout + o + 4) = f1;
      }
    }
  }

  const bf16* vb = vt + (size_t)bh * 64 * 512;
  f32x4 pacc[2];
  pacc[0] = (f32x4)(0.0f); pacc[1] = (f32x4)(0.0f);
  const int ra = rowg + ln15;
  const int rsw = ((ln15 >> 2) & 3) << 1;
  #pragma unroll
  for (int h2 = 0; h2 < 2; h2++) {
    #pragma unroll
    for (int kk = 0; kk < 8; kk++) {
      int gg = kk * 4 + quad;
      bf16x8 a = *(bf16x8*)&P[ra * 512 + h2 * 256 + ((gg ^ rsw) * 8)];
      int k0 = h2 * 256 + kk * 32;
      #pragma unroll
      for (int nt2 = 0; nt2 < 2; nt2++) {
        int dcol = ch * 32 + nt2 * 16 + ln15;
        bf16x8 b = *(const bf16x8*)(vb + (size_t)dcol * 512 + k0 + quad * 8);
        pacc[nt2] = mfma_bf16(a, b, pacc[nt2]);
      }
    }
  }

  for (int rr = 1; rr < 32; rr++) {
    float av[4];
    #pragma unroll
    for (int r = 0; r < 4; r++) {
      int k = qg + r + rr - 16;
      av[r] = 0.f;
      if (k >= 0 && k < 512) {
        int g = k >> 3, chg = g >> 5, gg = g & 31;
        int slot = gg ^ (quad << 1);
        av[r] = us2f((unsigned short)P[(rowl0 + r) * 512 + chg * 256 +
                                       slot * 8 + (k & 7)]);
      }
    }
    #pragma unroll
    for (int nt2 = 0; nt2 < 2; nt2++) {
      float relv = us2f(relb[rr * 64 + ch * 32 + nt2 * 16 + ln15]);
      #pragma unroll
      for (int r = 0; r < 4; r++) pacc[nt2][r] += av[r] * relv;
    }
  }

  #pragma unroll
  for (int nt2 = 0; nt2 < 2; nt2++) {
    float r0v = us2f(relb[ch * 32 + nt2 * 16 + ln15]);
    float r32v = us2f(relb[32 * 64 + ch * 32 + nt2 * 16 + ln15]);
    #pragma unroll
    for (int r = 0; r < 4; r++)
      pacc[nt2][r] += sle[r] * inv[r] * r0v + sge[r] * inv[r] * r32v;
  }

  const int bl = bh >> 4, head = bh & 15;
  #pragma unroll
  for (int r = 0; r < 4; r++) {
    int s = qt * 32 + rowl0 + r;
    #pragma unroll
    for (int nt2 = 0; nt2 < 2; nt2++)
      ctx[((size_t)bl * 512 + s) * 1024 + head * 64 + ch * 32 + nt2 * 16 + ln15] =
          __float2bfloat16(pacc[nt2][r]);
  }
}

// ---------------------------------------------------------------------------
// Fused edge view v5 (round-15 verified, REVERTED from v6: the split-k ILP
// raised VGPR 48->68 and dropped occupancy 42->32%, regressing 135->144us —
// TLP beats ILP in this latency-bound kernel). Elementwise phase 1,
// unnormalized P, MFMA-ones row sums, epilogue normalization.
// ---------------------------------------------------------------------------
__global__ __launch_bounds__(256)
void edge_fused_k(const float* __restrict__ h0, const float* __restrict__ h1,
                  const unsigned char* __restrict__ maskp,
                  const bf16* __restrict__ vt, bf16* __restrict__ ctx5)
{
  __shared__ short P[32 * 512];   // 32 KB, UNNORMALIZED bf16 p
  const int tid = threadIdx.x;
  const int w = tid >> 6, ln = tid & 63;
  const int ln15 = ln & 15, quad = ln >> 4;
  const int bh = blockIdx.x, qt = blockIdx.y, view = blockIdx.z;
  const int bl = bh >> 4;
  bf16* ctx = ctx5 + (size_t)(1 + view) * 4194304;

  // ---- phase 1: rows w*8 .. w*8+7, elementwise only ----
  {
    const float* hjp = h1 + (size_t)view * 65536 + (size_t)bh * 512 + ln * 8;
    float4 hA = *(const float4*)hjp;
    float4 hB = *(const float4*)(hjp + 4);
    float hjv[8] = {hA.x * LOG2E, hA.y * LOG2E, hA.z * LOG2E, hA.w * LOG2E,
                    hB.x * LOG2E, hB.y * LOG2E, hB.z * LOG2E, hB.w * LOG2E};
    const float* h0b = h0 + (size_t)view * 65536 + (size_t)bh * 512 + qt * 32 + w * 8;
    const unsigned char* mrow = maskp + (size_t)view * 262144 + (size_t)bl * 32768
                                + (size_t)(qt * 32 + w * 8) * 64 + ln;
    #pragma unroll
    for (int rr = 0; rr < 8; rr++) {
      unsigned int mb = mrow[rr * 64];
      float hi = h0b[rr] * LOG2E;
      // all-masked row -> store 1.0 everywhere: MFMA rowsum = 512 exactly ->
      // ctx = sum(V)/512 (reference uniform).
      float fb = (__ballot(mb != 0) == 0ull) ? 1.0f : 0.0f;
      int r = w * 8 + rr;
      bf16x8 pv;
      #pragma unroll
      for (int j = 0; j < 8; j++) {
        float ej = hi + hjv[j];
        float lr = fmaxf(ej, 0.01f * ej);       // lrelu (log2-domain)
        float p = __builtin_amdgcn_exp2f(lr);
        p = ((mb >> j) & 1) ? p : fb;
        pv[j] = (short)f2us(p);
      }
      *(bf16x8*)&P[r * 512 + ((ln ^ (r & 7)) * 8)] = pv;
    }
  }
  __syncthreads();

  // ---- phase 2: acc = P@V^T, accs = P@ones (row sums); normalize at end ----
  bf16x8 ones;
  #pragma unroll
  for (int j = 0; j < 8; j++) ones[j] = (short)0x3F80;   // bf16 1.0
  const bf16* vb = vt + (size_t)bh * 64 * 512;
  const int m0 = (w >> 1) * 16, d0 = (w & 1) * 32;
  f32x4 acc[2], accs;
  acc[0] = (f32x4)(0.0f); acc[1] = (f32x4)(0.0f); accs = (f32x4)(0.0f);

  const int ra = m0 + ln15;
  const int rsw = ra & 7;
  #pragma unroll 4
  for (int k0 = 0; k0 < 512; k0 += 32) {
    int gsel = (k0 >> 3) + quad;
    bf16x8 a = *(bf16x8*)&P[ra * 512 + ((gsel ^ rsw) * 8)];
    #pragma unroll
    for (int nt = 0; nt < 2; nt++) {
      bf16x8 b = *(const bf16x8*)(vb + (size_t)(d0 + nt * 16 + ln15) * 512 + k0 + quad * 8);
      acc[nt] = mfma_bf16(a, b, acc[nt]);
    }
    accs = mfma_bf16(a, ones, accs);   // col-independent row sums
  }

  const int head = bh & 15;
  #pragma unroll
  for (int r = 0; r < 4; r++) {
    float inv = 1.0f / accs[r];        // sum > 0 always (1.0-fill if masked)
    int s = qt * 32 + m0 + quad * 4 + r;
    #pragma unroll
    for (int nt = 0; nt < 2; nt++)
      ctx[((size_t)bl * 512 + s) * 1024 + head * 64 + d0 + nt * 16 + ln15] =
          __float2bfloat16(acc[nt][r] * inv);
  }
}

// ---------------------------------------------------------------------------
// Gate GEMMs, z-batched over 5 views; async gload16 staging.
// ---------------------------------------------------------------------------
__global__ __launch_bounds__(256)
void gate_gemm_k(const bf16* __restrict__ ctx5, const bf16* __restrict__ Wt,
                 const void* __restrict__ gate_b, bf16* __restrict__ gated5,
                 const int* __restrict__ dflag)
{
  const int isbf = *dflag;
  const int z = blockIdx.z;
  const int gsel[5] = {0, 5, 1, 2, 3};
  const bf16* A = ctx5 + (size_t)z * 4194304;
  bf16* outB = gated5 + (size_t)z * 4194304;
  const bf16* Wz = Wt + (size_t)(3 + z) * WSL;
  const size_t boff = (size_t)gsel[z] * 1024;

  __shared__ short As[128 * 64];
  __shared__ short Bs[128 * 64];
  const int tid = threadIdx.x;
  const int w = tid >> 6, ln = tid & 63;
  const int ln15 = ln & 15, quad = ln >> 4;
  const int wm = (w & 1) * 64, wn = (w >> 1) * 64;
  const int bm = blockIdx.x * 128, bn = blockIdx.y * 128;
  const int rbase = w * 8 + (ln >> 3);
  const int goff = ((ln & 7) ^ (ln >> 3)) * 8;
  f32x4 acc[4][4];
  #pragma unroll
  for (int mt = 0; mt < 4; mt++)
    #pragma unroll
    for (int nt = 0; nt < 4; nt++) acc[mt][nt] = (f32x4)(0.0f);

  for (int k0 = 0; k0 < 1024; k0 += 64) {
    #pragma unroll
    for (int i = 0; i < 4; i++) {
      int r = i * 32 + rbase;
      gload16(A + (size_t)(bm + r) * 1024 + k0 + goff,
              &As[(i * 32 + w * 8) * 64]);
      gload16(Wz + (size_t)(bn + r) * 1024 + k0 + goff,
              &Bs[(i * 32 + w * 8) * 64]);
    }
    __syncthreads();
    #pragma unroll
    for (int s = 0; s < 2; s++) {
      bf16x8 af[4], bfr[4];
      #pragma unroll
      for (int t = 0; t < 4; t++) {
        int ra = wm + t * 16 + ln15;
        af[t] = *(bf16x8*)&As[ra * 64 + (((s * 4 + quad) ^ (ra & 7)) * 8)];
        int rb = wn + t * 16 + ln15;
        bfr[t] = *(bf16x8*)&Bs[rb * 64 + (((s * 4 + quad) ^ (rb & 7)) * 8)];
      }
      #pragma unroll
      for (int mt = 0; mt < 4; mt++)
        #pragma unroll
        for (int nt = 0; nt < 4; nt++)
          acc[mt][nt] = mfma_bf16(af[mt], bfr[nt], acc[mt][nt]);
    }
    __syncthreads();
  }

  #pragma unroll
  for (int nt = 0; nt < 4; nt++) {
    int col = bn + wn + nt * 16 + ln15;
    float bv = ldx(gate_b, boff + col, isbf);
    #pragma unroll
    for (int mt = 0; mt < 4; mt++) {
      #pragma unroll
      for (int r = 0; r < 4; r++) {
        int row = bm + wm + mt * 16 + quad * 4 + r;
        float v = acc[mt][nt][r] + bv;
        float x = bf2f(A[(size_t)row * 1024 + col]);
        outB[(size_t)row * 1024 + col] = __float2bfloat16(x / (1.f + __expf(-v)));
      }
    }
  }
}

// ---------------------------------------------------------------------------
// Sub GEMM, split-K x2 (round-12 verified): each z handles 2560 of K=5120,
// writes f32 partials into the dead ctx5 region; finish2_k combines + bias.
// ---------------------------------------------------------------------------
__global__ __launch_bounds__(256)
void sub_gemm_k(const bf16* __restrict__ gated5, const bf16* __restrict__ Wt,
                float* __restrict__ part)
{
  __shared__ short As[128 * 64];
  __shared__ short Bs[128 * 64];
  const int tid = threadIdx.x;
  const int w = tid >> 6, ln = tid & 63;
  const int ln15 = ln & 15, quad = ln >> 4;
  const int wm = (w & 1) * 64, wn = (w >> 1) * 64;
  const int bm = blockIdx.x * 128, bn = blockIdx.y * 128;
  const int zk = blockIdx.z;
  const int rbase = w * 8 + (ln >> 3);
  const int goff = ((ln & 7) ^ (ln >> 3)) * 8;
  f32x4 acc[4][4];
  #pragma unroll
  for (int mt = 0; mt < 4; mt++)
    #pragma unroll
    for (int nt = 0; nt < 4; nt++) acc[mt][nt] = (f32x4)(0.0f);

  for (int k0 = zk * 2560; k0 < (zk + 1) * 2560; k0 += 64) {
    const int slot = k0 >> 10, kk = k0 & 1023;
    const bf16* Ab = gated5 + (size_t)slot * 4194304;
    const bf16* Wz = Wt + (size_t)(8 + slot) * WSL;
    #pragma unroll
    for (int i = 0; i < 4; i++) {
      int r = i * 32 + rbase;
      gload16(Ab + (size_t)(bm + r) * 1024 + kk + goff,
              &As[(i * 32 + w * 8) * 64]);
      gload16(Wz + (size_t)(bn + r) * 1024 + kk + goff,
              &Bs[(i * 32 + w * 8) * 64]);
    }
    __syncthreads();
    #pragma unroll
    for (int s = 0; s < 2; s++) {
      bf16x8 af[4], bfr[4];
      #pragma unroll
      for (int t = 0; t < 4; t++) {
        int ra = wm + t * 16 + ln15;
        af[t] = *(bf16x8*)&As[ra * 64 + (((s * 4 + quad) ^ (ra & 7)) * 8)];
        int rb = wn + t * 16 + ln15;
        bfr[t] = *(bf16x8*)&Bs[rb * 64 + (((s * 4 + quad) ^ (rb & 7)) * 8)];
      }
      #pragma unroll
      for (int mt = 0; mt < 4; mt++)
        #pragma unroll
        for (int nt = 0; nt < 4; nt++)
          acc[mt][nt] = mfma_bf16(af[mt], bfr[nt], acc[mt][nt]);
    }
    __syncthreads();
  }

  float* pz = part + (size_t)zk * 4194304;
  #pragma unroll
  for (int nt = 0; nt < 4; nt++) {
    int col = bn + wn + nt * 16 + ln15;
    #pragma unroll
    for (int mt = 0; mt < 4; mt++) {
      #pragma unroll
      for (int r = 0; r < 4; r++) {
        int row = bm + wm + mt * 16 + quad * 4 + r;
        pz[(size_t)row * 1024 + col] = acc[mt][nt][r];
      }
    }
  }
}

// ---------------------------------------------------------------------------
// Combine split-K partials + sub_b -> d_out (dtype-aware).
// ---------------------------------------------------------------------------
__global__ __launch_bounds__(256)
void finish2_k(const float* __restrict__ part, const void* __restrict__ sub_b,
               void* __restrict__ dout, const int* __restrict__ dflag)
{
  const int isbf = *dflag;
  int i = blockIdx.x * 256 + threadIdx.x;
  float4 a = ((const float4*)part)[i];
  float4 b = ((const float4*)(part + 4194304))[i];
  int c = (i * 4) & 1023;
  float o0 = a.x + b.x + ldx(sub_b, c + 0, isbf);
  float o1 = a.y + b.y + ldx(sub_b, c + 1, isbf);
  float o2 = a.z + b.z + ldx(sub_b, c + 2, isbf);
  float o3 = a.w + b.w + ldx(sub_b, c + 3, isbf);
  if (isbf) {
    ushort4 u;
    u.x = f2us(o0); u.y = f2us(o1); u.z = f2us(o2); u.w = f2us(o3);
    ((ushort4*)dout)[i] = u;
  } else {
    ((float4*)dout)[i] = make_float4(o0, o1, o2, o3);
  }
}

// ---------------------------------------------------------------------------
extern "C" void kernel_launch(void* const* d_in, const int* in_sizes, int n_in,
                              void* d_out, int out_size, void* d_ws, size_t ws_size,
                              hipStream_t stream)
{
  const void* key   = d_in[0];
  const void* value = d_in[1];
  const void* query = d_in[2];
  const int*  grh   = (const int*)d_in[3];
  const void* Wq = d_in[5];
  const void* bq = d_in[6];
  const void* Wk = d_in[7];
  const void* bk = d_in[8];
  const void* Wv = d_in[9];
  const void* bv = d_in[10];
  const void* rel_emb = d_in[11];
  const void* att_w = d_in[12];
  const void* att_b = d_in[13];
  const void* gate_w = d_in[14];
  const void* gate_b = d_in[15];
  const void* sub_w = d_in[16];
  const void* sub_b = d_in[17];

  // workspace layout (floats) — same footprint as rounds 9-16 (~173 MB)
  int* dflag = (int*)d_ws;
  float* base = (float*)d_ws;
  bf16* qbf = (bf16*)(base + 16);
  bf16* kbf = (bf16*)(base + 16 + 2097152);
  bf16* vtb = (bf16*)(base + 16 + 2 * 2097152);
  bf16* Wt  = (bf16*)(base + 16 + 3 * 2097152);
  float* G  = base + 16 + 3 * 2097152 + 6815744;
  float* h0 = G + 2162688;
  float* h1 = h0 + 262144;
  bf16* ctx5   = (bf16*)(h1 + 262144);
  bf16* gated5 = ctx5 + 5ull * 4194304;
  unsigned char* maskp = (unsigned char*)(gated5 + 5ull * 4194304);
  bf16* qkvb = (bf16*)(maskp + 1048576);
  float* subpart = (float*)ctx5;   // ctx5 dead after gate_gemm; 33.5MB fits 42MB

  detect_k<<<dim3(1), dim3(64), 0, stream>>>(Wq, dflag);

  // merged pre-pass: cvt (6144) + wtrans (3328) + mask_pack (1024)
  prep_k<<<dim3(10496), dim3(256), 0, stream>>>(
      query, key, value, qkvb, grh, maskp, Wq, Wk, Wv, gate_w, sub_w, Wt, dflag);

  // QKV projections batched (z: 0=q scaled, 1=k, 2=v transposed)
  qkv_gemm_k<<<dim3(32, 8, 3), dim3(256), 0, stream>>>(
      qkvb, Wt, bq, bk, bv, qbf, kbf, vtb, dflag);

  // merged qrel (16384) + hv (512)
  qrel_hv_k<<<dim3(16896), dim3(256), 0, stream>>>(
      qbf, rel_emb, G, vtb, att_w, att_b, h0, h1, dflag);

  // main view fully fused -> ctx5 slot 0 (+ top_attn to d_out)
  score_fused_k<<<dim3(128, 16), dim3(256), 0, stream>>>(
      qbf, kbf, G, vtb, rel_emb, ctx5, d_out, dflag);

  // edge views fused softmax+PV -> ctx5 slots 1..4
  edge_fused_k<<<dim3(128, 16, 4), dim3(256), 0, stream>>>(
      h0, h1, maskp, vtb, ctx5);

  // 5 gate GEMMs batched, then split-K sub GEMM + combine
  gate_gemm_k<<<dim3(32, 8, 5), dim3(256), 0, stream>>>(
      ctx5, Wt, gate_b, gated5, dflag);
  sub_gemm_k<<<dim3(32, 8, 2), dim3(256), 0, stream>>>(
      gated5, Wt, subpart);
  finish2_k<<<dim3(4096), dim3(256), 0, stream>>>(
      subpart, sub_b, d_out, dflag);
}